// Round 1
// baseline (200.919 us; speedup 1.0000x reference)
//
#include <hip/hip_runtime.h>
#include <hip/hip_bf16.h>
#include <cstdint>
#include <cstddef>

// ---------------- types / helpers ----------------
typedef float  f32x4  __attribute__((ext_vector_type(4)));
typedef __bf16 bf16x8 __attribute__((ext_vector_type(8)));
typedef unsigned short u16x8 __attribute__((ext_vector_type(8)));

__device__ __forceinline__ unsigned short f2bf(float f) {
    unsigned u = __float_as_uint(f);
    u += 0x7FFFu + ((u >> 16) & 1u);   // round-to-nearest-even
    return (unsigned short)(u >> 16);
}

// ---------------- problem constants ----------------
// B=64, C=80, IN_CH=300, J=8192, S=8, OUT=1024
// feature [64,2048,14,14], out [64,80]

// ---------------- ws layout (bytes) ----------------
constexpr size_t OFF_FEATB = 0;                    // 64*2048 bf16      = 262144
constexpr size_t OFF_ADJ   = 262144;               // 80*80 f32         = 25600
constexpr size_t OFF_Y0    = 287744;               // 80*1024 f32       = 327680
constexpr size_t OFF_X1    = 615424;               // 80*1024 f32       = 327680
constexpr size_t OFF_X2B   = 943104;               // 80*1024 bf16      = 163840
constexpr size_t OFF_WG2T  = 1106944;              // 2048*1024 f32     = 8388608
constexpr size_t OFF_XB    = 9495552;              // 80*2048 bf16      = 327680
constexpr size_t OFF_IMG   = 9823232;              // 64*8192 f32       = 2097152
constexpr size_t OFF_CLS   = 11920384;             // 80*8192 f32       = 2621440
constexpr size_t OFF_G     = 14541824;             // 80*8192 f32       = 2621440
constexpr size_t OFF_PART  = 17163264;             // max 4*80*8192 f32 = 10485760
// total ~27.65 MB

// ---------------- kernels ----------------

// 1) feat[b,ch] = max over 196 spatial elems; write bf16. One wave per row.
__global__ __launch_bounds__(256) void maxpool_k(const float* __restrict__ feature,
                                                 unsigned short* __restrict__ featb) {
    int wid  = blockIdx.x * 4 + (threadIdx.x >> 6);      // row index in [0, 64*2048)
    int lane = threadIdx.x & 63;
    const float4* row = (const float4*)(feature + (size_t)wid * 196);
    float m = -1e30f;
    if (lane < 49) {                                     // 196 = 49 * float4
        float4 v = row[lane];
        m = fmaxf(fmaxf(v.x, v.y), fmaxf(v.z, v.w));
    }
    #pragma unroll
    for (int off = 32; off; off >>= 1) m = fmaxf(m, __shfl_xor(m, off));
    if (lane == 0) featb[wid] = f2bf(m);
}

// 2) adj[i,j] = A[j,i] * dinv[i] * dinv[j],  dinv = rowsum(A)^-0.5
__global__ void adj_kernel(const float* __restrict__ A, float* __restrict__ adj) {
    __shared__ float dinv[80];
    int t = threadIdx.x;
    if (t < 80) {
        float s = 0.f;
        for (int j = 0; j < 80; j++) s += A[t * 80 + j];
        dinv[t] = 1.0f / sqrtf(s);
    }
    __syncthreads();
    for (int idx = t; idx < 6400; idx += 256) {
        int i = idx / 80, j = idx % 80;
        adj[idx] = A[j * 80 + i] * dinv[i] * dinv[j];
    }
}

// 3) small f32 GEMM: out[c,j] = sum_k X[c,k] * W[k,j]; optional leaky / bf16 out.
//    grid: (N/256, C). X row is block-uniform (scalar loads).
__global__ __launch_bounds__(256) void gemm_small(const float* __restrict__ X,
                                                  const float* __restrict__ W,
                                                  float* __restrict__ outf,
                                                  unsigned short* __restrict__ outb,
                                                  int K, int N, int leaky) {
    int c = blockIdx.y;
    int j = blockIdx.x * 256 + threadIdx.x;
    const float* xr = X + (size_t)c * K;
    float acc = 0.f;
    #pragma unroll 4
    for (int k = 0; k < K; k++) acc = fmaf(xr[k], W[(size_t)k * N + j], acc);
    if (leaky && acc < 0.f) acc *= 0.2f;
    size_t o = (size_t)c * N + j;
    if (outf) outf[o] = acc;
    if (outb) outb[o] = f2bf(acc);
}

// 4) f32 transpose: out[C][R] = in[R][C]
__global__ __launch_bounds__(256) void transpose_f32(const float* __restrict__ in,
                                                     float* __restrict__ out,
                                                     int R, int C) {
    __shared__ float t[32][33];
    int r0 = blockIdx.y * 32, c0 = blockIdx.x * 32;
    int tx = threadIdx.x & 31, ty = threadIdx.x >> 5;    // 32 x 8
    #pragma unroll
    for (int i = 0; i < 32; i += 8) t[ty + i][tx] = in[(size_t)(r0 + ty + i) * C + c0 + tx];
    __syncthreads();
    #pragma unroll
    for (int i = 0; i < 32; i += 8) out[(size_t)(c0 + ty + i) * R + r0 + tx] = t[tx][ty + i];
}

// 5) MFMA GEMM: part[ks][m][n] = sum_{k in chunk} X[m,k] * W[n,k]
//    X: bf16 [MF*16][K] row-major, W: f32 [N][K] row-major (converted inline).
//    Block: 8 waves, each wave owns one 16-wide n-frag; BN = 128.
//    grid: (N/128, KSPLIT)
template <int MF>
__global__ __launch_bounds__(512) void mfma_gemm(const unsigned short* __restrict__ X,
                                                 const float* __restrict__ W,
                                                 float* __restrict__ part,
                                                 int N, int K, int kchunk) {
    int wave = threadIdx.x >> 6, lane = threadIdx.x & 63;
    int n = blockIdx.x * 128 + wave * 16 + (lane & 15);
    int row_a = lane & 15;
    int koff  = (lane >> 4) * 8;
    int k0    = blockIdx.y * kchunk;

    f32x4 acc[MF];
    #pragma unroll
    for (int i = 0; i < MF; i++) acc[i] = (f32x4)(0.f);

    const float* wrow = W + (size_t)n * K;

    #pragma unroll 2
    for (int k = k0; k < k0 + kchunk; k += 32) {
        // B fragment: 8 contiguous f32 from this W row -> bf16
        float4 w0 = *(const float4*)(wrow + k + koff);
        float4 w1 = *(const float4*)(wrow + k + koff + 4);
        u16x8 bu;
        bu[0] = f2bf(w0.x); bu[1] = f2bf(w0.y); bu[2] = f2bf(w0.z); bu[3] = f2bf(w0.w);
        bu[4] = f2bf(w1.x); bu[5] = f2bf(w1.y); bu[6] = f2bf(w1.z); bu[7] = f2bf(w1.w);
        bf16x8 bf = __builtin_bit_cast(bf16x8, bu);
        #pragma unroll
        for (int mf = 0; mf < MF; mf++) {
            u16x8 au = *(const u16x8*)(X + (size_t)(mf * 16 + row_a) * K + k + koff);
            bf16x8 af = __builtin_bit_cast(bf16x8, au);
            acc[mf] = __builtin_amdgcn_mfma_f32_16x16x32_bf16(af, bf, acc[mf], 0, 0, 0);
        }
    }

    const int M = MF * 16;
    float* p = part + (size_t)blockIdx.y * M * N;
    int r0 = (lane >> 4) * 4;
    #pragma unroll
    for (int mf = 0; mf < MF; mf++)
        #pragma unroll
        for (int i = 0; i < 4; i++)
            p[(size_t)(mf * 16 + r0 + i) * N + n] = acc[mf][i];
}

// 6) reduce K-split partials + bias; optional f32 / bf16 outputs.
__global__ __launch_bounds__(256) void reduce_bias(const float* __restrict__ part,
                                                   const float* __restrict__ bias,
                                                   float* __restrict__ outf,
                                                   unsigned short* __restrict__ outb,
                                                   int MN, int N, int S) {
    int idx = blockIdx.x * 256 + threadIdx.x;
    if (idx >= MN) return;
    float s = 0.f;
    for (int i = 0; i < S; i++) s += part[(size_t)i * MN + idx];
    if (bias) s += bias[idx & (N - 1)];   // N is a power of two here
    if (outf) outf[idx] = s;
    if (outb) outb[idx] = f2bf(s);
}

// 7) G[c2,j] = sum_c cls[c,j] * W_ml[c2, c*1024 + (j>>3)]
//    block: 16 c2 x 128 j (16 o). W_ml slice staged in LDS (64B-contiguous loads).
__global__ __launch_bounds__(256) void g_kernel(const float* __restrict__ cls,
                                                const float* __restrict__ W_ml,
                                                float* __restrict__ G) {
    __shared__ float wml[16][80][16];        // 80 KiB
    int c2b = blockIdx.y * 16;
    int o0  = blockIdx.x * 16;
    int j0  = o0 * 8;
    for (int idx = threadIdx.x; idx < 16 * 80 * 16; idx += 256) {
        int ol = idx & 15, c = (idx >> 4) % 80, c2 = idx / 1280;
        wml[c2][c][ol] = W_ml[(size_t)(c2b + c2) * 81920 + c * 1024 + o0 + ol];
    }
    __syncthreads();
    int jl  = threadIdx.x & 127;
    int c2l = (threadIdx.x >> 7) * 8;
    int ol  = jl >> 3;
    float acc[8] = {0.f, 0.f, 0.f, 0.f, 0.f, 0.f, 0.f, 0.f};
    for (int c = 0; c < 80; c++) {
        float cv = cls[(size_t)c * 8192 + j0 + jl];
        #pragma unroll
        for (int i = 0; i < 8; i++) acc[i] = fmaf(cv, wml[c2l + i][c][ol], acc[i]);
    }
    #pragma unroll
    for (int i = 0; i < 8; i++) G[(size_t)(c2b + c2l + i) * 8192 + j0 + jl] = acc[i];
}

// 8) part5[kc,b,c2] = sum_{k in chunk} img[b,k] * G[c2,k]
//    grid: (4 bgroups, 10 c2groups, 8 kchunks); wave handles 4 b x 8 c2.
__global__ __launch_bounds__(256) void dot_kernel(const float* __restrict__ img,
                                                  const float* __restrict__ G,
                                                  float* __restrict__ part5) {
    int bg = blockIdx.x, cg = blockIdx.y, kc = blockIdx.z;
    int w = threadIdx.x >> 6, lane = threadIdx.x & 63;
    int b0 = bg * 16 + w * 4;
    float acc[4][8];
    #pragma unroll
    for (int q = 0; q < 4; q++)
        #pragma unroll
        for (int i = 0; i < 8; i++) acc[q][i] = 0.f;

    for (int step = 0; step < 4; step++) {
        int k = kc * 1024 + step * 256 + lane * 4;
        float4 gv[8];
        #pragma unroll
        for (int i = 0; i < 8; i++) gv[i] = *(const float4*)(G + (size_t)(cg * 8 + i) * 8192 + k);
        #pragma unroll
        for (int q = 0; q < 4; q++) {
            float4 iv = *(const float4*)(img + (size_t)(b0 + q) * 8192 + k);
            #pragma unroll
            for (int i = 0; i < 8; i++) {
                acc[q][i] = fmaf(iv.x, gv[i].x, acc[q][i]);
                acc[q][i] = fmaf(iv.y, gv[i].y, acc[q][i]);
                acc[q][i] = fmaf(iv.z, gv[i].z, acc[q][i]);
                acc[q][i] = fmaf(iv.w, gv[i].w, acc[q][i]);
            }
        }
    }
    #pragma unroll
    for (int q = 0; q < 4; q++)
        #pragma unroll
        for (int i = 0; i < 8; i++) {
            float v = acc[q][i];
            #pragma unroll
            for (int off = 32; off; off >>= 1) v += __shfl_xor(v, off);
            if (lane == 0) part5[(size_t)(kc * 64 + b0 + q) * 80 + cg * 8 + i] = v;
        }
}

// 9) out[b,c2] = sum_kc part5 + b_ml[c2]
__global__ void final_out(const float* __restrict__ part5,
                          const float* __restrict__ b_ml,
                          float* __restrict__ out) {
    int idx = blockIdx.x * 256 + threadIdx.x;
    if (idx >= 5120) return;
    int b = idx / 80, c2 = idx % 80;
    float s = b_ml[c2];
    for (int kc = 0; kc < 8; kc++) s += part5[(size_t)(kc * 64 + b) * 80 + c2];
    out[idx] = s;
}

// ---------------- launch ----------------
extern "C" void kernel_launch(void* const* d_in, const int* in_sizes, int n_in,
                              void* d_out, int out_size, void* d_ws, size_t ws_size,
                              hipStream_t stream) {
    (void)in_sizes; (void)n_in; (void)out_size; (void)ws_size;
    const float* feature = (const float*)d_in[0];
    const float* inp     = (const float*)d_in[1];
    const float* A       = (const float*)d_in[2];
    const float* W_gc1   = (const float*)d_in[3];
    const float* W_gc2   = (const float*)d_in[4];
    const float* W_img   = (const float*)d_in[5];
    const float* b_img   = (const float*)d_in[6];
    const float* W_cls   = (const float*)d_in[7];
    const float* b_cls   = (const float*)d_in[8];
    const float* W_ml    = (const float*)d_in[9];
    const float* b_ml    = (const float*)d_in[10];
    float* out = (float*)d_out;
    char*  ws  = (char*)d_ws;

    unsigned short* featb = (unsigned short*)(ws + OFF_FEATB);
    float* adj  = (float*)(ws + OFF_ADJ);
    float* y0   = (float*)(ws + OFF_Y0);
    float* x1   = (float*)(ws + OFF_X1);
    unsigned short* x2b = (unsigned short*)(ws + OFF_X2B);
    float* wg2t = (float*)(ws + OFF_WG2T);
    unsigned short* xb  = (unsigned short*)(ws + OFF_XB);
    float* img  = (float*)(ws + OFF_IMG);
    float* cls  = (float*)(ws + OFF_CLS);
    float* G    = (float*)(ws + OFF_G);
    float* part = (float*)(ws + OFF_PART);
    float* part5 = (float*)(ws + OFF_PART);   // reused after last reduce

    // backbone max-pool -> feat bf16
    maxpool_k<<<32768, 256, 0, stream>>>(feature, featb);
    // adjacency
    adj_kernel<<<1, 256, 0, stream>>>(A, adj);
    // GCN: y0 = inp @ W_gc1 ; x1 = leaky(adj @ y0) ; x2 = adj @ x1 (bf16)
    gemm_small<<<dim3(4, 80), 256, 0, stream>>>(inp,  W_gc1, y0, nullptr, 300, 1024, 0);
    gemm_small<<<dim3(4, 80), 256, 0, stream>>>(adj,  y0,    x1, nullptr,  80, 1024, 1);
    gemm_small<<<dim3(4, 80), 256, 0, stream>>>(adj,  x1, nullptr, x2b,    80, 1024, 0);
    // x = x2 @ W_gc2 via MFMA on W_gc2^T  (M=80, N=2048, K=1024)
    transpose_f32<<<dim3(64, 32), 256, 0, stream>>>(W_gc2, wg2t, 1024, 2048);
    mfma_gemm<5><<<dim3(16, 4), 512, 0, stream>>>(x2b, wg2t, part, 2048, 1024, 256);
    reduce_bias<<<640, 256, 0, stream>>>(part, nullptr, nullptr, xb, 80 * 2048, 2048, 4);
    // img = feat @ W_img^T + b_img  (M=64, N=8192, K=2048)
    mfma_gemm<4><<<dim3(64, 4), 512, 0, stream>>>(featb, W_img, part, 8192, 2048, 512);
    reduce_bias<<<2048, 256, 0, stream>>>(part, b_img, img, nullptr, 64 * 8192, 8192, 4);
    // cls = x @ W_cls^T + b_cls  (M=80, N=8192, K=2048)
    mfma_gemm<5><<<dim3(64, 4), 512, 0, stream>>>(xb, W_cls, part, 8192, 2048, 512);
    reduce_bias<<<2560, 256, 0, stream>>>(part, b_cls, cls, nullptr, 80 * 8192, 8192, 4);
    // G[c2,j] = sum_c cls[c,j] * W_ml[c2, c*1024 + (j>>3)]
    g_kernel<<<dim3(64, 5), 256, 0, stream>>>(cls, W_ml, G);
    // out = img . G^T + b_ml
    dot_kernel<<<dim3(4, 10, 8), 256, 0, stream>>>(img, G, part5);
    final_out<<<20, 256, 0, stream>>>(part5, b_ml, out);
}

// Round 2
// 155.757 us; speedup vs baseline: 1.2900x; 1.2900x over previous
//
#include <hip/hip_runtime.h>
#include <hip/hip_bf16.h>
#include <cstdint>
#include <cstddef>

// ---------------- types / helpers ----------------
typedef float  f32x4  __attribute__((ext_vector_type(4)));
typedef __bf16 bf16x8 __attribute__((ext_vector_type(8)));
typedef unsigned short u16x8 __attribute__((ext_vector_type(8)));

__device__ __forceinline__ unsigned short f2bf(float f) {
    unsigned u = __float_as_uint(f);
    u += 0x7FFFu + ((u >> 16) & 1u);   // round-to-nearest-even
    return (unsigned short)(u >> 16);
}

// ---------------- problem constants ----------------
// B=64, C=80, IN_CH=300, J=8192, S=8, OUT=1024
// feature [64,2048,14,14], out [64,80]

// ---------------- ws layout (bytes) ----------------
constexpr size_t OFF_FEATB = 0;          // 64*2048 bf16  = 262144
constexpr size_t OFF_ADJ   = 262144;     // 80*80 f32     = 25600
constexpr size_t OFF_Y0    = 287744;     // 80*1024 f32   = 327680
constexpr size_t OFF_X1    = 615424;     // 80*1024 f32   = 327680
constexpr size_t OFF_X2B   = 943104;     // 80*1024 bf16  = 163840
constexpr size_t OFF_WG2T  = 1106944;    // 2048*1024 f32 = 8388608
constexpr size_t OFF_XB    = 9495552;    // 80*2048 bf16  = 327680
constexpr size_t OFF_IMG   = 9823232;    // 64*8192 f32   = 2097152
constexpr size_t OFF_CLS   = 11920384;   // 80*8192 f32   = 2621440
constexpr size_t OFF_G     = 14541824;   // 80*8192 f32   = 2621440
// total ~17.2 MB

// =================== roles (device functions) ===================

// maxpool: 16 lanes per row, 4 rows per wave, 128 rows per 512-thread block.
__device__ __forceinline__ void maxpool_role(int bid, const float* __restrict__ feature,
                                             unsigned short* __restrict__ featb) {
    int wave = threadIdx.x >> 6, lane = threadIdx.x & 63;
    int r = lane >> 4, q = lane & 15;
    #pragma unroll
    for (int it = 0; it < 4; ++it) {
        int row = bid * 128 + it * 32 + wave * 4 + r;
        const float4* p = (const float4*)(feature + (size_t)row * 196);
        float4 a = p[q], b = p[q + 16], c = p[q + 32];
        float m = fmaxf(fmaxf(fmaxf(a.x, a.y), fmaxf(a.z, a.w)),
                 fmaxf(fmaxf(fmaxf(b.x, b.y), fmaxf(b.z, b.w)),
                       fmaxf(fmaxf(c.x, c.y), fmaxf(c.z, c.w))));
        if (q == 0) {                       // 49th float4 (indices 192..195)
            float4 d = p[48];
            m = fmaxf(m, fmaxf(fmaxf(d.x, d.y), fmaxf(d.z, d.w)));
        }
        #pragma unroll
        for (int off = 1; off < 16; off <<= 1) m = fmaxf(m, __shfl_xor(m, off));
        if (q == 0) featb[row] = f2bf(m);
    }
}

// transpose W_gc2 [1024][2048] -> wg2t [2048][1024], 64x64 tiles, 512 threads
__device__ __forceinline__ void transpose_role(int idx, const float* __restrict__ in,
                                               float* __restrict__ out, float* t /*64*65*/) {
    int c0 = (idx & 31) * 64, r0 = (idx >> 5) * 64;
    int tx = threadIdx.x & 63, ty = threadIdx.x >> 6;   // 64 x 8
    #pragma unroll
    for (int i = 0; i < 64; i += 8)
        t[(ty + i) * 65 + tx] = in[(size_t)(r0 + ty + i) * 2048 + c0 + tx];
    __syncthreads();
    #pragma unroll
    for (int i = 0; i < 64; i += 8)
        out[(size_t)(c0 + ty + i) * 1024 + r0 + tx] = t[tx * 65 + (ty + i)];
}

// y0[c,j] = sum_k inp[c,k] * W_gc1[k,j]   (K=300, N=1024), 512 thr, 2 blocks/c
__device__ __forceinline__ void y0_role(int idx, const float* __restrict__ inp,
                                        const float* __restrict__ W1, float* __restrict__ y0) {
    int c = idx >> 1;
    int j = (idx & 1) * 512 + threadIdx.x;
    const float* xr = inp + c * 300;
    float acc = 0.f;
    #pragma unroll 4
    for (int k = 0; k < 300; k++) acc = fmaf(xr[k], W1[k * 1024 + j], acc);
    y0[c * 1024 + j] = acc;
}

// adj[i,j] = A[j,i] * dinv[i] * dinv[j]
__device__ __forceinline__ void adj_role(const float* __restrict__ A, float* __restrict__ adjp,
                                         float* dinv /* >=80 floats LDS */) {
    int t = threadIdx.x;
    if (t < 80) {
        float s = 0.f;
        for (int j = 0; j < 80; j++) s += A[t * 80 + j];
        dinv[t] = 1.0f / sqrtf(s);
    }
    __syncthreads();
    for (int i = t; i < 6400; i += 512) {
        int r = i / 80, cc = i % 80;
        adjp[i] = A[cc * 80 + r] * dinv[r] * dinv[cc];
    }
}

// x_out[c,j] = (leaky?)(sum_k adj[c,k] * xin[k,j])  K=80, N=1024
__device__ __forceinline__ void adjmul_role(int idx, const float* __restrict__ adjp,
                                            const float* __restrict__ xin,
                                            float* __restrict__ outf,
                                            unsigned short* __restrict__ outb, int leaky) {
    int c = idx >> 1;
    int j = (idx & 1) * 512 + threadIdx.x;
    const float* ar = adjp + c * 80;
    float acc = 0.f;
    #pragma unroll 4
    for (int k = 0; k < 80; k++) acc = fmaf(ar[k], xin[k * 1024 + j], acc);
    if (leaky && acc < 0.f) acc *= 0.2f;
    if (outf) outf[c * 1024 + j] = acc;
    if (outb) outb[c * 1024 + j] = f2bf(acc);
}

// MFMA GEMM with in-block K-split: out[m,n] = sum_k X[m,k]*W[n,k] (+bias[n])
// block = 8 waves: 2 n-frags x 4 k-splits; BN=32; LDS reduce; f32/bf16 out.
template <int MF>
__device__ __forceinline__ void gemm_block(int bx, const unsigned short* __restrict__ X,
                                           const float* __restrict__ W,
                                           const float* __restrict__ bias,
                                           float* __restrict__ outf,
                                           unsigned short* __restrict__ outb,
                                           int N, int K, float (*red)[64][21]) {
    int tid = threadIdx.x;
    int wave = tid >> 6, lane = tid & 63;
    int nf = wave & 1, ks = wave >> 1;
    int n = bx * 32 + nf * 16 + (lane & 15);
    int rowa = lane & 15;
    int koff = (lane >> 4) * 8;
    int Kc = K >> 2;
    int k0 = ks * Kc;

    f32x4 acc[MF];
    #pragma unroll
    for (int i = 0; i < MF; i++) acc[i] = (f32x4)(0.f);

    const float* wrow = W + (size_t)n * K;

    #pragma unroll 2
    for (int k = k0; k < k0 + Kc; k += 32) {
        float4 w0 = *(const float4*)(wrow + k + koff);
        float4 w1 = *(const float4*)(wrow + k + koff + 4);
        u16x8 bu;
        bu[0] = f2bf(w0.x); bu[1] = f2bf(w0.y); bu[2] = f2bf(w0.z); bu[3] = f2bf(w0.w);
        bu[4] = f2bf(w1.x); bu[5] = f2bf(w1.y); bu[6] = f2bf(w1.z); bu[7] = f2bf(w1.w);
        bf16x8 bf = __builtin_bit_cast(bf16x8, bu);
        #pragma unroll
        for (int mf = 0; mf < MF; mf++) {
            u16x8 au = *(const u16x8*)(X + (size_t)(mf * 16 + rowa) * K + k + koff);
            acc[mf] = __builtin_amdgcn_mfma_f32_16x16x32_bf16(
                __builtin_bit_cast(bf16x8, au), bf, acc[mf], 0, 0, 0);
        }
    }

    // stash per-wave partials (stride 21 -> conflict-free)
    #pragma unroll
    for (int mf = 0; mf < MF; mf++)
        #pragma unroll
        for (int i = 0; i < 4; i++)
            red[wave][lane][mf * 4 + i] = acc[mf][i];
    __syncthreads();

    // reduce 4 k-splits + bias + write
    int lane2 = tid & 63, sg = (tid >> 6) & 3, nf2 = tid >> 8;
    int n2 = bx * 32 + nf2 * 16 + (lane2 & 15);
    float b = bias ? bias[n2] : 0.f;
    #pragma unroll
    for (int mf = 0; mf < MF; mf++) {
        int slot = mf * 4 + sg;
        float s = red[0 + nf2][lane2][slot] + red[2 + nf2][lane2][slot]
                + red[4 + nf2][lane2][slot] + red[6 + nf2][lane2][slot] + b;
        int row = mf * 16 + (lane2 >> 4) * 4 + sg;
        size_t o = (size_t)row * N + n2;
        if (outf) outf[o] = s;
        if (outb) outb[o] = f2bf(s);
    }
}

// =================== kernels (7 dispatches) ===================

// K1: maxpool(1024) | transpose(512) | y0(160) | adj(1)  => 1697 blocks
__global__ __launch_bounds__(512) void k1(const float* __restrict__ feature,
                                          unsigned short* __restrict__ featb,
                                          const float* __restrict__ inp,
                                          const float* __restrict__ W1,
                                          float* __restrict__ y0,
                                          const float* __restrict__ A,
                                          float* __restrict__ adjp,
                                          const float* __restrict__ Wg2,
                                          float* __restrict__ wg2t) {
    __shared__ float lds[64 * 65];
    int b = blockIdx.x;
    if (b < 1024)       maxpool_role(b, feature, featb);
    else if (b < 1536)  transpose_role(b - 1024, Wg2, wg2t, lds);
    else if (b < 1696)  y0_role(b - 1536, inp, W1, y0);
    else                adj_role(A, adjp, lds);
}

// K2: x1 = leaky(adj@y0) (160) | img-gemm (256)  => 416 blocks
__global__ __launch_bounds__(512) void k2(const float* __restrict__ adjp,
                                          const float* __restrict__ y0,
                                          float* __restrict__ x1,
                                          const unsigned short* __restrict__ featb,
                                          const float* __restrict__ W_img,
                                          const float* __restrict__ b_img,
                                          float* __restrict__ img) {
    __shared__ float red[8][64][21];
    int b = blockIdx.x;
    if (b < 160) adjmul_role(b, adjp, y0, x1, nullptr, 1);
    else         gemm_block<4>(b - 160, featb, W_img, b_img, img, nullptr, 8192, 2048, red);
}

// K3: x2b = adj@x1 (bf16)  => 160 blocks
__global__ __launch_bounds__(512) void k3(const float* __restrict__ adjp,
                                          const float* __restrict__ x1,
                                          unsigned short* __restrict__ x2b) {
    adjmul_role(blockIdx.x, adjp, x1, nullptr, x2b, 0);
}

// K4: xb = x2 @ W_gc2 (via wg2t), M=80 N=2048 K=1024 -> bf16  => 64 blocks
__global__ __launch_bounds__(512) void k4(const unsigned short* __restrict__ x2b,
                                          const float* __restrict__ wg2t,
                                          unsigned short* __restrict__ xb) {
    __shared__ float red[8][64][21];
    gemm_block<5>(blockIdx.x, x2b, wg2t, nullptr, nullptr, xb, 2048, 1024, red);
}

// K5: cls = xb @ W_cls^T + b_cls, M=80 N=8192 K=2048  => 256 blocks
__global__ __launch_bounds__(512) void k5(const unsigned short* __restrict__ xb,
                                          const float* __restrict__ W_cls,
                                          const float* __restrict__ b_cls,
                                          float* __restrict__ cls) {
    __shared__ float red[8][64][21];
    gemm_block<5>(blockIdx.x, xb, W_cls, b_cls, cls, nullptr, 8192, 2048, red);
}

// K6: G[c2,j] = sum_c cls[c,j] * W_ml[c2, c*1024 + (j>>3)]   (proven kernel)
__global__ __launch_bounds__(256) void g_kernel(const float* __restrict__ cls,
                                                const float* __restrict__ W_ml,
                                                float* __restrict__ G) {
    __shared__ float wml[16][80][16];        // 80 KiB
    int c2b = blockIdx.y * 16;
    int o0  = blockIdx.x * 16;
    int j0  = o0 * 8;
    for (int idx = threadIdx.x; idx < 16 * 80 * 16; idx += 256) {
        int ol = idx & 15, c = (idx >> 4) % 80, c2 = idx / 1280;
        wml[c2][c][ol] = W_ml[(size_t)(c2b + c2) * 81920 + c * 1024 + o0 + ol];
    }
    __syncthreads();
    int jl  = threadIdx.x & 127;
    int c2l = (threadIdx.x >> 7) * 8;
    int ol  = jl >> 3;
    float acc[8] = {0.f, 0.f, 0.f, 0.f, 0.f, 0.f, 0.f, 0.f};
    for (int c = 0; c < 80; c++) {
        float cv = cls[(size_t)c * 8192 + j0 + jl];
        #pragma unroll
        for (int i = 0; i < 8; i++) acc[i] = fmaf(cv, wml[c2l + i][c][ol], acc[i]);
    }
    #pragma unroll
    for (int i = 0; i < 8; i++) G[(size_t)(c2b + c2l + i) * 8192 + j0 + jl] = acc[i];
}

// K7: out[b,c2] = sum_j img[b,j]*G[c2,j] + b_ml[c2]
// grid (16 btiles x 10 cgroups); 8 waves = 8 k-chunks; LDS reduce.
__global__ __launch_bounds__(512) void k7(const float* __restrict__ img,
                                          const float* __restrict__ G,
                                          const float* __restrict__ b_ml,
                                          float* __restrict__ out) {
    __shared__ float sm[8][32];
    int btile = blockIdx.x, cg = blockIdx.y;
    int kc = threadIdx.x >> 6, lane = threadIdx.x & 63;
    float acc[4][8];
    #pragma unroll
    for (int q = 0; q < 4; q++)
        #pragma unroll
        for (int i = 0; i < 8; i++) acc[q][i] = 0.f;

    #pragma unroll
    for (int step = 0; step < 4; step++) {
        int k = kc * 1024 + step * 256 + lane * 4;
        float4 gv[8];
        #pragma unroll
        for (int i = 0; i < 8; i++) gv[i] = *(const float4*)(G + (size_t)(cg * 8 + i) * 8192 + k);
        #pragma unroll
        for (int q = 0; q < 4; q++) {
            float4 iv = *(const float4*)(img + (size_t)(btile * 4 + q) * 8192 + k);
            #pragma unroll
            for (int i = 0; i < 8; i++) {
                acc[q][i] = fmaf(iv.x, gv[i].x, acc[q][i]);
                acc[q][i] = fmaf(iv.y, gv[i].y, acc[q][i]);
                acc[q][i] = fmaf(iv.z, gv[i].z, acc[q][i]);
                acc[q][i] = fmaf(iv.w, gv[i].w, acc[q][i]);
            }
        }
    }
    #pragma unroll
    for (int q = 0; q < 4; q++)
        #pragma unroll
        for (int i = 0; i < 8; i++) {
            float v = acc[q][i];
            #pragma unroll
            for (int off = 32; off; off >>= 1) v += __shfl_xor(v, off);
            if (lane == 0) sm[kc][q * 8 + i] = v;
        }
    __syncthreads();
    if (threadIdx.x < 32) {
        int i = threadIdx.x & 7;
        float s = b_ml[cg * 8 + i];
        #pragma unroll
        for (int kk = 0; kk < 8; kk++) s += sm[kk][threadIdx.x];
        int q = threadIdx.x >> 3;
        out[(size_t)(btile * 4 + q) * 80 + cg * 8 + i] = s;
    }
}

// ---------------- launch ----------------
extern "C" void kernel_launch(void* const* d_in, const int* in_sizes, int n_in,
                              void* d_out, int out_size, void* d_ws, size_t ws_size,
                              hipStream_t stream) {
    (void)in_sizes; (void)n_in; (void)out_size; (void)ws_size;
    const float* feature = (const float*)d_in[0];
    const float* inp     = (const float*)d_in[1];
    const float* A       = (const float*)d_in[2];
    const float* W_gc1   = (const float*)d_in[3];
    const float* W_gc2   = (const float*)d_in[4];
    const float* W_img   = (const float*)d_in[5];
    const float* b_img   = (const float*)d_in[6];
    const float* W_cls   = (const float*)d_in[7];
    const float* b_cls   = (const float*)d_in[8];
    const float* W_ml    = (const float*)d_in[9];
    const float* b_ml    = (const float*)d_in[10];
    float* out = (float*)d_out;
    char*  ws  = (char*)d_ws;

    unsigned short* featb = (unsigned short*)(ws + OFF_FEATB);
    float* adjp = (float*)(ws + OFF_ADJ);
    float* y0   = (float*)(ws + OFF_Y0);
    float* x1   = (float*)(ws + OFF_X1);
    unsigned short* x2b = (unsigned short*)(ws + OFF_X2B);
    float* wg2t = (float*)(ws + OFF_WG2T);
    unsigned short* xb  = (unsigned short*)(ws + OFF_XB);
    float* img  = (float*)(ws + OFF_IMG);
    float* cls  = (float*)(ws + OFF_CLS);
    float* G    = (float*)(ws + OFF_G);

    k1<<<1697, 512, 0, stream>>>(feature, featb, inp, W_gc1, y0, A, adjp, W_gc2, wg2t);
    k2<<<416,  512, 0, stream>>>(adjp, y0, x1, featb, W_img, b_img, img);
    k3<<<160,  512, 0, stream>>>(adjp, x1, x2b);
    k4<<<64,   512, 0, stream>>>(x2b, wg2t, xb);
    k5<<<256,  512, 0, stream>>>(xb, W_cls, b_cls, cls);
    g_kernel<<<dim3(64, 5), 256, 0, stream>>>(cls, W_ml, G);
    k7<<<dim3(16, 10), 512, 0, stream>>>(img, G, b_ml, out);
}